// Round 3
// baseline (282.129 us; speedup 1.0000x reference)
//
#include <hip/hip_runtime.h>

#define H 128
#define RNUM 8
#define TNUM 2
#define PNUM 1000
#define MNUM 223
#define BNODES 64           // nodes per dst-bucket (power of 2)
#define NBUCK 782           // padN / 64
#define BCAP 2304           // per-bucket capacity (mean 2048, +5.7 sigma)
#define EPB 4096            // edges per partition block (512 thr x 8)

typedef __attribute__((ext_vector_type(8))) short bf16x8;
typedef __attribute__((ext_vector_type(4))) float f32x4;

__device__ __forceinline__ float fsig(float z) {
    return 1.0f / (1.0f + __expf(-z));
}
__device__ __forceinline__ float fsig_fast(float z) {
    return __builtin_amdgcn_rcpf(1.0f + __expf(-z));
}

__device__ __forceinline__ float wave_reduce(float v) {
#pragma unroll
    for (int off = 32; off > 0; off >>= 1) v += __shfl_down(v, off, 64);
    return v;
}

__device__ __forceinline__ unsigned short f2bf(float f) {
    unsigned int u = __float_as_uint(f);
    u += 0x7fffu + ((u >> 16) & 1u);   // RNE
    return (unsigned short)(u >> 16);
}

// ---------------------------------------------------------------------------
// K1 (partition + setup fused, 512 threads):
//  blocks [0, NP):         edge partition (8 edges/thread, 8-deep ILP)
//  blocks [NP, NP+256):    wt/bias transpose+pad (4 p's per block)
//  blocks [NP+256, +4):    CbT bf16 precompute (4 tr per block)
// Payload 8B: .x = src | (local<<18) | (r<<24) | (t<<27)
//             .y = f0 | (f1<<10) | (f2<<20)   [pre-quantized fields]
// ---------------------------------------------------------------------------
__global__ __launch_bounds__(512) void partition_setup(
        const int* __restrict__ src, const int* __restrict__ dst,
        const int* __restrict__ etype, const float* __restrict__ norm,
        const int* __restrict__ node_type, const float* __restrict__ ntc,
        int* __restrict__ cursor,
        uint2* __restrict__ buck, int E, int NP,
        const float* __restrict__ fl3_w, const float* __restrict__ fl3_b,
        unsigned short* __restrict__ wt, float* __restrict__ biasws,
        const float* __restrict__ fc_w, const float* __restrict__ fc_b,
        const float* __restrict__ w_nt, const float* __restrict__ w_rel,
        unsigned short* __restrict__ CbT) {
    int blk = blockIdx.x;
    int tid = threadIdx.x;
    if (blk < NP) {
        // ------------- partition path -------------
        __shared__ int lh[NBUCK];
        __shared__ int gb[NBUCK];
        for (int i = tid; i < NBUCK; i += 512) lh[i] = 0;
        __syncthreads();
        int base = blk * EPB;
        uint2 pl[8]; int bb[8]; int rk[8];
#pragma unroll
        for (int c = 0; c < 8; ++c) {
            int e = base + c * 512 + tid;
            bb[c] = -1;
            if (e < E) {
                int s = src[e];
                int d = dst[e];
                int r = etype[e];
                float nm = norm[e];
                int t = node_type[s];
                float2 cc = ((const float2*)ntc)[s];
                unsigned f0 = __float2uint_rn(nm * cc.x * 128.0f);
                unsigned f1 = __float2uint_rn(nm * cc.y * 128.0f);
                unsigned f2 = __float2uint_rn(nm * 512.0f);
                int b = d >> 6;
                int local = d & 63;
                pl[c].x = (unsigned)s | ((unsigned)local << 18) | ((unsigned)r << 24) | ((unsigned)t << 27);
                pl[c].y = f0 | (f1 << 10) | (f2 << 20);
                bb[c] = b;
                rk[c] = atomicAdd(&lh[b], 1);
            }
        }
        __syncthreads();
        for (int i = tid; i < NBUCK; i += 512) {
            if (lh[i] > 0) {
                int g = atomicAdd(&cursor[i], lh[i]);
                gb[i] = (g < 0) ? 0 : (g > BCAP ? BCAP : g);
            }
        }
        __syncthreads();
#pragma unroll
        for (int c = 0; c < 8; ++c) {
            if (bb[c] >= 0) {
                int pos = gb[bb[c]] + rk[c];
                if (pos < BCAP) buck[(size_t)bb[c] * BCAP + pos] = pl[c];
            }
        }
    } else if (blk < NP + 256) {
        // ------------- wt transpose path (4 p's per block) -------------
        int p = (blk - NP) * 4 + (tid >> 7);   // 0..1023
        int k = tid & 127;
        float v = (p < PNUM) ? fl3_w[(size_t)k * PNUM + p] : 0.0f;
        wt[(size_t)p * H + k] = f2bf(v);
        if (k == 0) biasws[p] = (p < PNUM) ? fl3_b[p] : -1.0e4f;
    } else {
        // ------------- CbT path (4 tr per block) -------------
        __shared__ float G[4][3][H];
        int g = tid >> 7;                       // group 0..3
        int tr = (blk - NP - 256) * 4 + g;      // 0..15
        int t = tr >> 3, r = tr & 7;
        int i = tid & 127;
        float a0 = 0.f, a1 = 0.f, a2 = 0.f;
#pragma unroll 8
        for (int j = 0; j < H; ++j) {
            float w = w_nt[((size_t)t * H + j) * H + i];
            a0 += fc_w[j] * w;
            a1 += fc_w[H + j] * w;
            a2 += fc_b[j] * w;
        }
        G[g][0][i] = a0; G[g][1][i] = a1; G[g][2][i] = a2;
        __syncthreads();
        float c0 = 0.f, c1 = 0.f, c2 = 0.f;
#pragma unroll 8
        for (int k = 0; k < H; ++k) {
            float w = w_rel[((size_t)r * H + k) * H + i];
            c0 += G[g][0][k] * w;
            c1 += G[g][1][k] * w;
            c2 += G[g][2][k] * w;
        }
        CbT[i * 64 + tr * 3 + 0] = f2bf(c0);
        CbT[i * 64 + tr * 3 + 1] = f2bf(c1);
        CbT[i * 64 + tr * 3 + 2] = f2bf(c2);
        if (tr == 0) {
            uint4 z = make_uint4(0u, 0u, 0u, 0u);
            *(uint4*)(CbT + i * 64 + 48) = z;
            *(uint4*)(CbT + i * 64 + 56) = z;
        }
    }
}

// ---------------------------------------------------------------------------
// K3: per-bucket: replay (packed u64 LDS atomics) -> S -> GEMM1 (h, MFMA)
// -> pred, gsum partial -> h bf16 into LDS (reusing S region) -> GEMM2 vs
// global wt (L2-hot, no staging) -> sigmoid-sum -> psum[bkt].
// hb is GONE: prob3 fused here, no HBM round-trip for h.
// ---------------------------------------------------------------------------
__global__ __launch_bounds__(256) void bucket_node(
        const uint2* __restrict__ buck, const int* __restrict__ cursor,
        const unsigned short* __restrict__ CbT,
        const float* __restrict__ fc2_w, const float* __restrict__ fc2_b,
        const unsigned short* __restrict__ wt, const float* __restrict__ biasws,
        float* __restrict__ pred, float* __restrict__ gpart,
        float* __restrict__ psum, int N) {
    __shared__ float S[64 * 68];            // union: replay P -> S f32 -> h bf16
    __shared__ unsigned short Cb[128 * 72]; // CbT rows padded to 72 shorts
    __shared__ float gloc[128];
    __shared__ float red[4];
    unsigned long long* P = (unsigned long long*)S;   // 64*16 u64 = first 2048 floats
    unsigned short* hsh = (unsigned short*)S;         // 64 rows x 136 shorts = 17408B = sizeof(S)
    int tid = threadIdx.x;
    int bkt = blockIdx.x;
    for (int i = tid; i < 2048; i += 256) S[i] = 0.0f;   // zero P region
    for (int g = tid; g < 1024; g += 256) {   // stage CbT: 1024 uint4
        int row = g >> 3, c = g & 7;
        uint4 v = ((const uint4*)CbT)[g];
        *(uint4*)(Cb + row * 72 + c * 8) = v;
    }
    if (tid < 128) gloc[tid] = 0.0f;
    __syncthreads();

    int cnt = cursor[bkt];
    if (cnt > BCAP) cnt = BCAP;
    if (cnt < 0) cnt = 0;
    const uint2* bp = buck + (size_t)bkt * BCAP;
    for (int base = 0; base < cnt; base += 1024) {
        uint2 pl[4]; int ii[4];
#pragma unroll
        for (int j = 0; j < 4; ++j) {
            ii[j] = base + j * 256 + tid;
            pl[j] = (ii[j] < cnt) ? bp[ii[j]] : make_uint2(0u, 0u);
        }
#pragma unroll
        for (int j = 0; j < 4; ++j) {
            if (ii[j] < cnt) {
                int local = (pl[j].x >> 18) & 63;
                int tr = ((pl[j].x >> 24) & 7) + (((pl[j].x >> 27) & 1) << 3);
                unsigned y = pl[j].y;
                unsigned long long pk = (unsigned long long)(y & 1023u)
                                      | ((unsigned long long)((y >> 10) & 1023u) << 21)
                                      | ((unsigned long long)(y >> 20) << 42);
                atomicAdd(&P[local * 16 + tr], pk);
            }
        }
    }
    __syncthreads();

    // unpack P -> registers (1024 u64, 4 per thread), then rebuild S
    unsigned long long rpk[4];
#pragma unroll
    for (int u = 0; u < 4; ++u) rpk[u] = P[tid * 4 + u];
    __syncthreads();
#pragma unroll
    for (int u = 0; u < 4; ++u) {
        int idx = tid * 4 + u;
        int local = idx >> 4, tr = idx & 15;
        float* p = S + local * 68 + tr * 3;
        p[0] = (float)(unsigned)(rpk[u] & 0x1FFFFFull) * (1.0f / 128.0f);
        p[1] = (float)(unsigned)((rpk[u] >> 21) & 0x1FFFFFull) * (1.0f / 128.0f);
        p[2] = (float)(unsigned)(rpk[u] >> 42) * (1.0f / 512.0f);
    }
    for (int idx = tid; idx < 1024; idx += 256) {   // zero pad cols 48..63
        int row = idx >> 4, c = idx & 15;
        S[row * 68 + 48 + c] = 0.0f;
    }
    __syncthreads();

    int lane = tid & 63, w = tid >> 6;
    int lrow = lane & 15, quad = lane >> 4;

    // A-frags: rows w*16+lrow of S (fp32 -> bf16)
    bf16x8 a[2];
#pragma unroll
    for (int ks = 0; ks < 2; ++ks) {
        const float* sp = S + (w * 16 + lrow) * 68 + ks * 32 + quad * 8;
        float4 f0 = *(const float4*)sp;
        float4 f1 = *(const float4*)(sp + 4);
        bf16x8 t;
        t[0] = (short)f2bf(f0.x); t[1] = (short)f2bf(f0.y);
        t[2] = (short)f2bf(f0.z); t[3] = (short)f2bf(f0.w);
        t[4] = (short)f2bf(f1.x); t[5] = (short)f2bf(f1.y);
        t[6] = (short)f2bf(f1.z); t[7] = (short)f2bf(f1.w);
        a[ks] = t;
    }
    __syncthreads();   // all waves done READING S before hsh overwrite below

    f32x4 acc[8];
#pragma unroll
    for (int tn = 0; tn < 8; ++tn) acc[tn] = (f32x4){0.f, 0.f, 0.f, 0.f};
#pragma unroll
    for (int ks = 0; ks < 2; ++ks) {
#pragma unroll
        for (int tn = 0; tn < 8; ++tn) {
            bf16x8 b = *(const bf16x8*)(Cb + (tn * 16 + lrow) * 72 + ks * 32 + quad * 8);
            acc[tn] = __builtin_amdgcn_mfma_f32_16x16x32_bf16(a[ks], b, acc[tn], 0, 0, 0);
        }
    }

    // relu
#pragma unroll
    for (int tn = 0; tn < 8; ++tn)
#pragma unroll
        for (int r = 0; r < 4; ++r) acc[tn][r] = fmaxf(acc[tn][r], 0.f);

    // h (bf16) into LDS over the old S region: row = w*16+quad*4+r, col = tn*16+lrow
    int vbase = bkt * BNODES + w * 16 + quad * 4;
#pragma unroll
    for (int r = 0; r < 4; ++r) {
        unsigned short* hrow = hsh + (w * 16 + quad * 4 + r) * 136 + lrow;
#pragma unroll
        for (int tn = 0; tn < 8; ++tn) hrow[tn * 16] = f2bf(acc[tn][r]);
    }
    // pred: dot over 128 cols = reduce over 16 lanes of the quad
    float pd[4];
#pragma unroll
    for (int r = 0; r < 4; ++r) {
        float s = 0.f;
#pragma unroll
        for (int tn = 0; tn < 8; ++tn) s += acc[tn][r] * fc2_w[tn * 16 + lrow];
        pd[r] = s;
    }
#pragma unroll
    for (int mask = 1; mask < 16; mask <<= 1)
#pragma unroll
        for (int r = 0; r < 4; ++r) pd[r] += __shfl_xor(pd[r], mask, 64);
    if (lrow == 0) {
#pragma unroll
        for (int r = 0; r < 4; ++r) {
            int v = vbase + r;
            if (v < N) {
                float z = pd[r] + fc2_b[0];
                pred[v] = fminf(fmaxf(fsig(z), 1e-7f), 1e10f);
            }
        }
    }
    // gsum partial: column sums over this wave's 16 rows
    float csum[8];
#pragma unroll
    for (int tn = 0; tn < 8; ++tn)
        csum[tn] = acc[tn][0] + acc[tn][1] + acc[tn][2] + acc[tn][3];
#pragma unroll
    for (int mask = 16; mask < 64; mask <<= 1)
#pragma unroll
        for (int tn = 0; tn < 8; ++tn) csum[tn] += __shfl_xor(csum[tn], mask, 64);
    if (lane < 16) {
#pragma unroll
        for (int tn = 0; tn < 8; ++tn) atomicAdd(&gloc[tn * 16 + lrow], csum[tn]);
    }
    __syncthreads();   // covers gloc atomics AND hsh writes
    if (tid < 128) gpart[(size_t)bkt * 128 + tid] = gloc[tid];

    // ---------------- GEMM2: prob3 = sum sigmoid(h @ wt^T + bias) ----------
    // Wave w owns A rows w*16..w*16+15; B-frags read straight from global wt
    // (256 KB, L2-resident). No LDS staging, no extra barriers.
    bf16x8 a2[4];
#pragma unroll
    for (int ks = 0; ks < 4; ++ks)
        a2[ks] = *(const bf16x8*)(hsh + (w * 16 + lrow) * 136 + ks * 32 + quad * 8);

    float lsum = 0.f;
    for (int pt = 0; pt < 8; ++pt) {
        f32x4 acc2[8];
#pragma unroll
        for (int tn = 0; tn < 8; ++tn) acc2[tn] = (f32x4){0.f, 0.f, 0.f, 0.f};
#pragma unroll
        for (int ks = 0; ks < 4; ++ks) {
            bf16x8 b[8];
#pragma unroll
            for (int tn = 0; tn < 8; ++tn)
                b[tn] = *(const bf16x8*)(wt + (size_t)(pt * 128 + tn * 16 + lrow) * H + ks * 32 + quad * 8);
#pragma unroll
            for (int tn = 0; tn < 8; ++tn)
                acc2[tn] = __builtin_amdgcn_mfma_f32_16x16x32_bf16(a2[ks], b[tn], acc2[tn], 0, 0, 0);
        }
#pragma unroll
        for (int tn = 0; tn < 8; ++tn) {
            float bv = biasws[pt * 128 + tn * 16 + lrow];
#pragma unroll
            for (int r = 0; r < 4; ++r)
                lsum += fsig_fast(acc2[tn][r] + bv);
        }
    }
    lsum = wave_reduce(lsum);
    if (lane == 0) red[w] = lsum;
    __syncthreads();
    if (tid == 0) psum[bkt] = red[0] + red[1] + red[2] + red[3];
}

// ---------------------------------------------------------------------------
// K4 (MEGA): remaining post-bucket_node work (prob3 moved into K3).
//  [0, nbuck):        bucketed agg_outcost (LDS accumulate, buck replay)
//  [.., +2*MNUM):     row/col sums (+ce/sq on rows)
//  [.., +128):        gsum dim-reduction
// ---------------------------------------------------------------------------
__global__ __launch_bounds__(256) void mega_kernel(
        const uint2* __restrict__ buck, const int* __restrict__ cursor,
        const float* __restrict__ pred, const float* __restrict__ sc,
        const float* __restrict__ gt, float* __restrict__ ocpart, int N,
        float* __restrict__ rs, float* __restrict__ cs,
        float* __restrict__ cepart, float* __restrict__ sqpart,
        const float* __restrict__ gpart, float* __restrict__ gsum, int nbuck) {
    __shared__ float aggl[BNODES];
    __shared__ float red[12];
    int blk = blockIdx.x;
    int tid = threadIdx.x;
    int P1 = nbuck;
    int P2 = P1 + 2 * MNUM;

    if (blk < P1) {
        // ---------------- agg_outcost path (bucketed, LDS accumulate) -----
        int bkt = blk;
        if (tid < BNODES) aggl[tid] = 0.0f;
        __syncthreads();
        int cnt = cursor[bkt];
        if (cnt > BCAP) cnt = BCAP;
        if (cnt < 0) cnt = 0;
        const uint2* bp = buck + (size_t)bkt * BCAP;
        for (int base = 0; base < cnt; base += 2048) {
            unsigned x[8]; float pv[8]; int ii[8];
#pragma unroll
            for (int j = 0; j < 8; ++j) {
                ii[j] = base + j * 256 + tid;
                x[j] = (ii[j] < cnt) ? bp[ii[j]].x : 0u;
            }
#pragma unroll
            for (int j = 0; j < 8; ++j)
                pv[j] = (ii[j] < cnt) ? pred[x[j] & 0x3FFFF] : 0.f;
#pragma unroll
            for (int j = 0; j < 8; ++j)
                if (ii[j] < cnt) atomicAdd(&aggl[(x[j] >> 18) & 63], pv[j]);
        }
        __syncthreads();
        if (tid < 64) {
            float v = 0.f;
            int node = bkt * BNODES + tid;
            if (node < N) {
                float d = aggl[tid] - 1.0f;
                v = d * d * sc[node];
            }
            v = wave_reduce(v);
            if (tid == 0) ocpart[bkt] = v;
        }
    } else if (blk < P2) {
        // ---------------- rowcol path (+ce/sq on rows) ----------------
        int rc = blk - P1;
        if (rc < MNUM) {
            float p = 0.f, ce = 0.f, sq = 0.f;
            if (tid < MNUM) {
                p = pred[rc * MNUM + tid];
                ce = -gt[rc * MNUM + tid] * __log2f(p);
                sq = p * p;
            }
            p = wave_reduce(p);
            ce = wave_reduce(ce);
            sq = wave_reduce(sq);
            int wid = tid >> 6;
            if ((tid & 63) == 0) { red[wid] = p; red[4 + wid] = ce; red[8 + wid] = sq; }
            __syncthreads();
            if (tid == 0) {
                rs[rc] = red[0] + red[1] + red[2] + red[3];
                cepart[rc] = red[4] + red[5] + red[6] + red[7];
                sqpart[rc] = red[8] + red[9] + red[10] + red[11];
            }
        } else {
            int j = rc - MNUM;
            float p = 0.f;
            if (tid < MNUM) p = pred[tid * MNUM + j];
            p = wave_reduce(p);
            if ((tid & 63) == 0) red[tid >> 6] = p;
            __syncthreads();
            if (tid == 0) cs[j] = red[0] + red[1] + red[2] + red[3];
        }
    } else {
        // ---------------- gsum dim-reduction ----------------
        int dim = blk - P2;  // 0..127
        float s = 0.f;
        for (int b = tid; b < nbuck; b += 256) s += gpart[(size_t)b * 128 + dim];
        s = wave_reduce(s);
        if ((tid & 63) == 0) red[tid >> 6] = s;
        __syncthreads();
        if (tid == 0) gsum[dim] = red[0] + red[1] + red[2] + red[3];
    }
}

// K8: single-block tail (1024 threads): all six outputs via plain stores.
__global__ __launch_bounds__(1024) void tail_kernel(
        const float* __restrict__ rs, const float* __restrict__ cs,
        const float* __restrict__ cepart, const float* __restrict__ sqpart,
        const float* __restrict__ psum, int npsum,
        const float* __restrict__ ocpart, int nbuck,
        const float* __restrict__ gsum, const float* __restrict__ fc3_w,
        const float* __restrict__ fc3_b, const float* __restrict__ fl3_b,
        float* __restrict__ out, int N, int padrows) {
    __shared__ float red[16];
    int tid = threadIdx.x;
    int wid = tid >> 6, lane = tid & 63;
    // sumone
    float v = 0.f;
    if (tid < MNUM) {
        float a = rs[tid] - 1.0f, b = cs[tid] - 1.0f;
        v = a * a + b * b;
    }
    v = wave_reduce(v);
    if (lane == 0) red[wid] = v;
    __syncthreads();
    if (tid == 0) { float s = 0.f; for (int i = 0; i < 16; ++i) s += red[i]; out[1] = s; }
    __syncthreads();
    // ce
    float ce = (tid < MNUM) ? cepart[tid] : 0.f;
    ce = wave_reduce(ce);
    if (lane == 0) red[wid] = ce;
    __syncthreads();
    if (tid == 0) { float s = 0.f; for (int i = 0; i < 16; ++i) s += red[i]; out[3] = s; }
    __syncthreads();
    // loss2 = sum rs^2 + sum cs^2 - 2 sum p^2
    float l2 = 0.f;
    if (tid < MNUM)
        l2 = rs[tid] * rs[tid] + cs[tid] * cs[tid] - 2.0f * sqpart[tid];
    l2 = wave_reduce(l2);
    if (lane == 0) red[wid] = l2;
    __syncthreads();
    if (tid == 0) { float s = 0.f; for (int i = 0; i < 16; ++i) s += red[i]; out[2] = s; }
    __syncthreads();
    // prob3_sum
    float ps = 0.f;
    for (int i = tid; i < npsum; i += 1024) ps += psum[i];
    float ss = 0.f;
    for (int p = tid; p < PNUM; p += 1024) ss += fsig_fast(fl3_b[p]);
    float comb = ps - (float)padrows * ss;
    comb = wave_reduce(comb);
    if (lane == 0) red[wid] = comb;
    __syncthreads();
    if (tid == 0) { float s = 0.f; for (int i = 0; i < 16; ++i) s += red[i]; out[5] = s; }
    __syncthreads();
    // out_cost
    float oc = 0.f;
    for (int b = tid; b < nbuck; b += 1024) oc += ocpart[b];
    oc = wave_reduce(oc);
    if (lane == 0) red[wid] = oc;
    __syncthreads();
    if (tid == 0) { float s = 0.f; for (int i = 0; i < 16; ++i) s += red[i]; out[4] = s; }
    __syncthreads();
    // pred_obj
    float pv = 0.f;
    if (tid < 128) pv = gsum[tid] * (1.0f / (float)N) * fc3_w[tid];
    pv = wave_reduce(pv);
    if (lane == 0) red[wid] = pv;
    __syncthreads();
    if (tid == 0) { float s = 0.f; for (int i = 0; i < 16; ++i) s += red[i]; out[0] = s + fc3_b[0]; }
}

extern "C" void kernel_launch(void* const* d_in, const int* in_sizes, int n_in,
                              void* d_out, int out_size, void* d_ws, size_t ws_size,
                              hipStream_t stream) {
    const float* ntc   = (const float*)d_in[0];
    const float* norm  = (const float*)d_in[1];
    const float* sc    = (const float*)d_in[2];
    const float* gt    = (const float*)d_in[3];
    const float* fc_w  = (const float*)d_in[4];
    const float* fc_b  = (const float*)d_in[5];
    const float* w_nt  = (const float*)d_in[6];
    const float* w_rel = (const float*)d_in[7];
    const float* fc2_w = (const float*)d_in[8];
    const float* fc2_b = (const float*)d_in[9];
    const float* fc3_w = (const float*)d_in[10];
    const float* fc3_b = (const float*)d_in[11];
    const float* fl3_w = (const float*)d_in[12];
    const float* fl3_b = (const float*)d_in[13];
    const int* node_type = (const int*)d_in[14];
    const int* src   = (const int*)d_in[15];
    const int* dst   = (const int*)d_in[16];
    const int* etype = (const int*)d_in[17];
    int N = in_sizes[2];
    int E = in_sizes[1];
    int nb128 = (N + 127) / 128;             // 391
    int padN  = nb128 * 128;                 // 50048
    int nbuck = padN / BNODES;               // 782
    int NP = (E + EPB - 1) / EPB;            // 391

    // ---- workspace layout (float offsets) ----
    float* ws   = (float*)d_ws;
    unsigned short* wt = (unsigned short*)ws;            // 0..65536 (131072 shorts)
    float* biasws = ws + 65536;              // ..66560
    float* gsum = ws + 66560;                // ..66688
    float* rs   = ws + 66688;                // ..66944
    float* cs   = ws + 66944;                // ..67200
    int*  cursor = (int*)(ws + 67200);       // ..67984 (784 ints)
    float* psum = ws + 67984;                // ..69008 (782 used)
    float* cepart = ws + 69008;              // ..69264
    float* sqpart = ws + 69264;              // ..69520
    float* ocpart = ws + 69520;              // ..70544
    unsigned short* CbT = (unsigned short*)(ws + 70544); // 8192 shorts -> ..74640
    float* gpart  = ws + 74640;              // ..174736 (782*128)
    float* pred = ws + 174736;               // ..+N
    uint2* buck = (uint2*)(pred + N + 64);   // nbuck*BCAP*8B
    float* out  = (float*)d_out;

    hipMemsetAsync(cursor, 0, 784 * sizeof(int), stream);

    partition_setup<<<NP + 260, 512, 0, stream>>>(src, dst, etype, norm, node_type, ntc,
                                                  cursor, buck, E, NP,
                                                  fl3_w, fl3_b, wt, biasws,
                                                  fc_w, fc_b, w_nt, w_rel, CbT);
    bucket_node<<<nbuck, 256, 0, stream>>>(buck, cursor, CbT, fc2_w, fc2_b,
                                           wt, biasws, pred, gpart, psum, N);
    int megablocks = nbuck + 2 * MNUM + 128;
    mega_kernel<<<megablocks, 256, 0, stream>>>(buck, cursor, pred, sc, gt, ocpart, N,
                                                rs, cs, cepart, sqpart, gpart, gsum, nbuck);
    tail_kernel<<<1, 1024, 0, stream>>>(rs, cs, cepart, sqpart, psum, nbuck, ocpart, nbuck,
                                        gsum, fc3_w, fc3_b, fl3_b, out, N, padN - N);
}

// Round 4
// 191.156 us; speedup vs baseline: 1.4759x; 1.4759x over previous
//
#include <hip/hip_runtime.h>

#define H 128
#define RNUM 8
#define TNUM 2
#define PNUM 1000
#define MNUM 223
#define BNODES 64           // nodes per dst-bucket (power of 2)
#define NBUCK 782           // padN / 64
#define BCAP 2304           // per-bucket capacity (mean 2048, +5.7 sigma)
#define EPB 8192            // edges per partition block (1024 thr x 8)
#define CPAD 16             // cursor padding: 1 cursor per 64B cache line

typedef __attribute__((ext_vector_type(8))) short bf16x8;
typedef __attribute__((ext_vector_type(4))) float f32x4;

__device__ __forceinline__ float fsig(float z) {
    return 1.0f / (1.0f + __expf(-z));
}
__device__ __forceinline__ float fsig_fast(float z) {
    return __builtin_amdgcn_rcpf(1.0f + __expf(-z));
}

__device__ __forceinline__ float wave_reduce(float v) {
#pragma unroll
    for (int off = 32; off > 0; off >>= 1) v += __shfl_down(v, off, 64);
    return v;
}

__device__ __forceinline__ unsigned short f2bf(float f) {
    unsigned int u = __float_as_uint(f);
    u += 0x7fffu + ((u >> 16) & 1u);   // RNE
    return (unsigned short)(u >> 16);
}

// ---------------------------------------------------------------------------
// K1 (partition + setup fused, 1024 threads):
//  blocks [0, NP):         edge partition (8 consecutive edges/thread, int4 loads)
//  blocks [NP, NP+128):    wt/bias transpose+pad (8 p's per block)
//  blocks [NP+128, +2):    CbT bf16 precompute (8 tr per block)
// Payload 8B: .x = src | (local<<18) | (r<<24) | (t<<27)
//             .y = f0 | (f1<<10) | (f2<<20)   [pre-quantized fields]
// Cursor is padded to one per cache line (CPAD) so the per-bucket global
// atomics from different blocks never share a line: per-line serialized
// RMWs drop from ~6200 to ~196.
// ---------------------------------------------------------------------------
__global__ __launch_bounds__(1024) void partition_setup(
        const int* __restrict__ src, const int* __restrict__ dst,
        const int* __restrict__ etype, const float* __restrict__ norm,
        const int* __restrict__ node_type, const float* __restrict__ ntc,
        int* __restrict__ cursor,
        uint2* __restrict__ buck, int E, int NP,
        const float* __restrict__ fl3_w, const float* __restrict__ fl3_b,
        unsigned short* __restrict__ wt, float* __restrict__ biasws,
        const float* __restrict__ fc_w, const float* __restrict__ fc_b,
        const float* __restrict__ w_nt, const float* __restrict__ w_rel,
        unsigned short* __restrict__ CbT) {
    int blk = blockIdx.x;
    int tid = threadIdx.x;
    if (blk < NP) {
        // ------------- partition path -------------
        __shared__ int lh[NBUCK];
        __shared__ int gb[NBUCK];
        for (int i = tid; i < NBUCK; i += 1024) lh[i] = 0;
        __syncthreads();
        int base = blk * EPB;
        int e0 = base + tid * 8;
        int s[8], d[8], r[8]; float nm[8];
        if (e0 + 8 <= E) {
            *(int4*)(s)      = ((const int4*)(src + e0))[0];
            *(int4*)(s + 4)  = ((const int4*)(src + e0))[1];
            *(int4*)(d)      = ((const int4*)(dst + e0))[0];
            *(int4*)(d + 4)  = ((const int4*)(dst + e0))[1];
            *(int4*)(r)      = ((const int4*)(etype + e0))[0];
            *(int4*)(r + 4)  = ((const int4*)(etype + e0))[1];
            *(float4*)(nm)     = ((const float4*)(norm + e0))[0];
            *(float4*)(nm + 4) = ((const float4*)(norm + e0))[1];
        } else {
#pragma unroll
            for (int c = 0; c < 8; ++c) {
                int e = e0 + c;
                bool ok = (e < E);
                s[c] = ok ? src[e] : 0;
                d[c] = ok ? dst[e] : 0;
                r[c] = ok ? etype[e] : 0;
                nm[c] = ok ? norm[e] : 0.0f;
            }
        }
        int t8[8]; float2 cc8[8];
#pragma unroll
        for (int c = 0; c < 8; ++c) {
            t8[c] = node_type[s[c]];
            cc8[c] = ((const float2*)ntc)[s[c]];
        }
        uint2 pl[8]; int bb[8]; int rk[8];
#pragma unroll
        for (int c = 0; c < 8; ++c) {
            bb[c] = -1;
            if (e0 + c < E) {
                unsigned f0 = __float2uint_rn(nm[c] * cc8[c].x * 128.0f);
                unsigned f1 = __float2uint_rn(nm[c] * cc8[c].y * 128.0f);
                unsigned f2 = __float2uint_rn(nm[c] * 512.0f);
                int b = d[c] >> 6;
                int local = d[c] & 63;
                pl[c].x = (unsigned)s[c] | ((unsigned)local << 18) | ((unsigned)r[c] << 24) | ((unsigned)t8[c] << 27);
                pl[c].y = f0 | (f1 << 10) | (f2 << 20);
                bb[c] = b;
                rk[c] = atomicAdd(&lh[b], 1);
            }
        }
        __syncthreads();
        for (int i = tid; i < NBUCK; i += 1024) {
            if (lh[i] > 0) {
                int g = atomicAdd(&cursor[i * CPAD], lh[i]);
                gb[i] = (g < 0) ? 0 : (g > BCAP ? BCAP : g);
            }
        }
        __syncthreads();
#pragma unroll
        for (int c = 0; c < 8; ++c) {
            if (bb[c] >= 0) {
                int pos = gb[bb[c]] + rk[c];
                if (pos < BCAP) buck[(size_t)bb[c] * BCAP + pos] = pl[c];
            }
        }
    } else if (blk < NP + 128) {
        // ------------- wt transpose path (8 p's per block) -------------
        int p = (blk - NP) * 8 + (tid >> 7);   // 0..1023
        int k = tid & 127;
        float v = (p < PNUM) ? fl3_w[(size_t)k * PNUM + p] : 0.0f;
        wt[(size_t)p * H + k] = f2bf(v);
        if (k == 0) biasws[p] = (p < PNUM) ? fl3_b[p] : -1.0e4f;
    } else {
        // ------------- CbT path (8 tr per block) -------------
        __shared__ float G[8][3][H];
        int g = tid >> 7;                       // group 0..7
        int tr = (blk - NP - 128) * 8 + g;      // 0..15
        int t = tr >> 3, r = tr & 7;
        int i = tid & 127;
        float a0 = 0.f, a1 = 0.f, a2 = 0.f;
#pragma unroll 8
        for (int j = 0; j < H; ++j) {
            float w = w_nt[((size_t)t * H + j) * H + i];
            a0 += fc_w[j] * w;
            a1 += fc_w[H + j] * w;
            a2 += fc_b[j] * w;
        }
        G[g][0][i] = a0; G[g][1][i] = a1; G[g][2][i] = a2;
        __syncthreads();
        float c0 = 0.f, c1 = 0.f, c2 = 0.f;
#pragma unroll 8
        for (int k = 0; k < H; ++k) {
            float w = w_rel[((size_t)r * H + k) * H + i];
            c0 += G[g][0][k] * w;
            c1 += G[g][1][k] * w;
            c2 += G[g][2][k] * w;
        }
        CbT[i * 64 + tr * 3 + 0] = f2bf(c0);
        CbT[i * 64 + tr * 3 + 1] = f2bf(c1);
        CbT[i * 64 + tr * 3 + 2] = f2bf(c2);
        if (tr == 0) {
            uint4 z = make_uint4(0u, 0u, 0u, 0u);
            *(uint4*)(CbT + i * 64 + 48) = z;
            *(uint4*)(CbT + i * 64 + 56) = z;
        }
    }
}

// ---------------------------------------------------------------------------
// K3: per-bucket replay with ONE packed u64 LDS atomic per edge.
// Then h = relu(S@C) via bf16 MFMA; hb bf16, pred, gsum partial.
// ---------------------------------------------------------------------------
__global__ __launch_bounds__(256) void bucket_node(
        const uint2* __restrict__ buck, const int* __restrict__ cursor,
        const unsigned short* __restrict__ CbT,
        const float* __restrict__ fc2_w, const float* __restrict__ fc2_b,
        unsigned short* __restrict__ hb, float* __restrict__ pred,
        float* __restrict__ gpart, int N) {
    __shared__ float S[64 * 68];            // union: replay P, then S
    __shared__ unsigned short Cb[128 * 72]; // CbT rows padded to 72 shorts
    __shared__ float gloc[128];
    unsigned long long* P = (unsigned long long*)S;   // 64*16 u64 = first 2048 floats
    int tid = threadIdx.x;
    int bkt = blockIdx.x;
    for (int i = tid; i < 2048; i += 256) S[i] = 0.0f;   // zero P region
    for (int g = tid; g < 1024; g += 256) {   // stage CbT: 1024 uint4
        int row = g >> 3, c = g & 7;
        uint4 v = ((const uint4*)CbT)[g];
        *(uint4*)(Cb + row * 72 + c * 8) = v;
    }
    if (tid < 128) gloc[tid] = 0.0f;
    __syncthreads();

    int cnt = cursor[bkt * CPAD];
    if (cnt > BCAP) cnt = BCAP;
    if (cnt < 0) cnt = 0;
    const uint2* bp = buck + (size_t)bkt * BCAP;
    for (int base = 0; base < cnt; base += 1024) {
        uint2 pl[4]; int ii[4];
#pragma unroll
        for (int j = 0; j < 4; ++j) {
            ii[j] = base + j * 256 + tid;
            pl[j] = (ii[j] < cnt) ? bp[ii[j]] : make_uint2(0u, 0u);
        }
#pragma unroll
        for (int j = 0; j < 4; ++j) {
            if (ii[j] < cnt) {
                int local = (pl[j].x >> 18) & 63;
                int tr = ((pl[j].x >> 24) & 7) + (((pl[j].x >> 27) & 1) << 3);
                unsigned y = pl[j].y;
                unsigned long long pk = (unsigned long long)(y & 1023u)
                                      | ((unsigned long long)((y >> 10) & 1023u) << 21)
                                      | ((unsigned long long)(y >> 20) << 42);
                atomicAdd(&P[local * 16 + tr], pk);
            }
        }
    }
    __syncthreads();

    // unpack P -> registers (1024 u64, 4 per thread), then rebuild S
    unsigned long long rpk[4];
#pragma unroll
    for (int u = 0; u < 4; ++u) rpk[u] = P[tid * 4 + u];
    __syncthreads();
#pragma unroll
    for (int u = 0; u < 4; ++u) {
        int idx = tid * 4 + u;
        int local = idx >> 4, tr = idx & 15;
        float* p = S + local * 68 + tr * 3;
        p[0] = (float)(unsigned)(rpk[u] & 0x1FFFFFull) * (1.0f / 128.0f);
        p[1] = (float)(unsigned)((rpk[u] >> 21) & 0x1FFFFFull) * (1.0f / 128.0f);
        p[2] = (float)(unsigned)(rpk[u] >> 42) * (1.0f / 512.0f);
    }
    for (int idx = tid; idx < 1024; idx += 256) {   // zero pad cols 48..63
        int row = idx >> 4, c = idx & 15;
        S[row * 68 + 48 + c] = 0.0f;
    }
    __syncthreads();

    int lane = tid & 63, w = tid >> 6;
    int lrow = lane & 15, quad = lane >> 4;

    // A-frags: rows w*16+lrow of S (fp32 -> bf16)
    bf16x8 a[2];
#pragma unroll
    for (int ks = 0; ks < 2; ++ks) {
        const float* sp = S + (w * 16 + lrow) * 68 + ks * 32 + quad * 8;
        float4 f0 = *(const float4*)sp;
        float4 f1 = *(const float4*)(sp + 4);
        bf16x8 t;
        t[0] = (short)f2bf(f0.x); t[1] = (short)f2bf(f0.y);
        t[2] = (short)f2bf(f0.z); t[3] = (short)f2bf(f0.w);
        t[4] = (short)f2bf(f1.x); t[5] = (short)f2bf(f1.y);
        t[6] = (short)f2bf(f1.z); t[7] = (short)f2bf(f1.w);
        a[ks] = t;
    }

    f32x4 acc[8];
#pragma unroll
    for (int tn = 0; tn < 8; ++tn) acc[tn] = (f32x4){0.f, 0.f, 0.f, 0.f};
#pragma unroll
    for (int ks = 0; ks < 2; ++ks) {
#pragma unroll
        for (int tn = 0; tn < 8; ++tn) {
            bf16x8 b = *(const bf16x8*)(Cb + (tn * 16 + lrow) * 72 + ks * 32 + quad * 8);
            acc[tn] = __builtin_amdgcn_mfma_f32_16x16x32_bf16(a[ks], b, acc[tn], 0, 0, 0);
        }
    }

    // relu
#pragma unroll
    for (int tn = 0; tn < 8; ++tn)
#pragma unroll
        for (int r = 0; r < 4; ++r) acc[tn][r] = fmaxf(acc[tn][r], 0.f);

    int vbase = bkt * BNODES + w * 16 + quad * 4;
#pragma unroll
    for (int r = 0; r < 4; ++r) {
        unsigned short* hrow = hb + (size_t)(vbase + r) * H + lrow;
#pragma unroll
        for (int tn = 0; tn < 8; ++tn) hrow[tn * 16] = f2bf(acc[tn][r]);
    }
    // pred: dot over 128 cols = reduce over 16 lanes of the quad
    float pd[4];
#pragma unroll
    for (int r = 0; r < 4; ++r) {
        float s = 0.f;
#pragma unroll
        for (int tn = 0; tn < 8; ++tn) s += acc[tn][r] * fc2_w[tn * 16 + lrow];
        pd[r] = s;
    }
#pragma unroll
    for (int mask = 1; mask < 16; mask <<= 1)
#pragma unroll
        for (int r = 0; r < 4; ++r) pd[r] += __shfl_xor(pd[r], mask, 64);
    if (lrow == 0) {
#pragma unroll
        for (int r = 0; r < 4; ++r) {
            int v = vbase + r;
            if (v < N) {
                float z = pd[r] + fc2_b[0];
                pred[v] = fminf(fmaxf(fsig(z), 1e-7f), 1e10f);
            }
        }
    }
    // gsum partial: column sums over this wave's 16 rows
    float csum[8];
#pragma unroll
    for (int tn = 0; tn < 8; ++tn)
        csum[tn] = acc[tn][0] + acc[tn][1] + acc[tn][2] + acc[tn][3];
#pragma unroll
    for (int mask = 16; mask < 64; mask <<= 1)
#pragma unroll
        for (int tn = 0; tn < 8; ++tn) csum[tn] += __shfl_xor(csum[tn], mask, 64);
    if (lane < 16) {
#pragma unroll
        for (int tn = 0; tn < 8; ++tn) atomicAdd(&gloc[tn * 16 + lrow], csum[tn]);
    }
    __syncthreads();
    if (tid < 128) gpart[(size_t)bkt * 128 + tid] = gloc[tid];
}

// ---------------------------------------------------------------------------
// K4 (MEGA): all post-bucket_node independent work in ONE launch.
//  [0, nb128):        prob3 GEMM+sigmoid (one block per 128 nodes, all 8 pt)
//  [.., +nbuck):      bucketed agg_outcost (LDS accumulate, buck replay)
//  [.., +2*MNUM):     row/col sums (+ce/sq on rows)
//  [.., +128):        gsum dim-reduction
// ---------------------------------------------------------------------------
__global__ __launch_bounds__(256, 2) void mega_kernel(
        const unsigned short* __restrict__ hb, const unsigned short* __restrict__ wt,
        const float* __restrict__ biasws, float* __restrict__ psum, int nb128,
        const uint2* __restrict__ buck, const int* __restrict__ cursor,
        const float* __restrict__ pred, const float* __restrict__ sc,
        const float* __restrict__ gt, float* __restrict__ ocpart, int N,
        float* __restrict__ rs, float* __restrict__ cs,
        float* __restrict__ cepart, float* __restrict__ sqpart,
        const float* __restrict__ gpart, float* __restrict__ gsum, int nbuck) {
    __shared__ unsigned short Bsh[128 * 136];
    __shared__ float red[12];
    int blk = blockIdx.x;
    int tid = threadIdx.x;
    int P1 = nb128;
    int P2 = P1 + nbuck;
    int P3 = P2 + 2 * MNUM;

    if (blk < P1) {
        // ---------------- prob3 path (single pass over hb) ----------------
        int n0 = blk * 128;
        int lane = tid & 63, wid = tid >> 6;
        int wy = wid >> 1, wx = wid & 1;
        int lrow = lane & 15, quad = lane >> 4;

        bf16x8 a[4][4];
#pragma unroll
        for (int tm = 0; tm < 4; ++tm) {
            const unsigned short* arow = hb + (size_t)(n0 + wy * 64 + tm * 16 + lrow) * H + quad * 8;
#pragma unroll
            for (int ks = 0; ks < 4; ++ks)
                a[tm][ks] = *(const bf16x8*)(arow + ks * 32);
        }

        float lsum = 0.f;
        for (int pt = 0; pt < 8; ++pt) {
            __syncthreads();
            {
                int c = tid & 15;
                int r0 = tid >> 4;
#pragma unroll
                for (int it = 0; it < 8; ++it) {
                    int row = r0 + it * 16;
                    uint4 bv = *(const uint4*)(wt + (size_t)(pt * 128 + row) * H + c * 8);
                    *(uint4*)(Bsh + row * 136 + c * 8) = bv;
                }
            }
            __syncthreads();

            f32x4 acc[4][4];
#pragma unroll
            for (int tm = 0; tm < 4; ++tm)
#pragma unroll
                for (int tn = 0; tn < 4; ++tn)
                    acc[tm][tn] = (f32x4){0.f, 0.f, 0.f, 0.f};

            const unsigned short* Bbase = Bsh + (wx * 64 + lrow) * 136 + quad * 8;
#pragma unroll
            for (int ks = 0; ks < 4; ++ks) {
                bf16x8 b[4];
#pragma unroll
                for (int tn = 0; tn < 4; ++tn)
                    b[tn] = *(const bf16x8*)(Bbase + tn * 16 * 136 + ks * 32);
#pragma unroll
                for (int tm = 0; tm < 4; ++tm)
#pragma unroll
                    for (int tn = 0; tn < 4; ++tn)
                        acc[tm][tn] = __builtin_amdgcn_mfma_f32_16x16x32_bf16(a[tm][ks], b[tn], acc[tm][tn], 0, 0, 0);
            }

#pragma unroll
            for (int tn = 0; tn < 4; ++tn) {
                float bv = biasws[pt * 128 + wx * 64 + tn * 16 + lrow];
#pragma unroll
                for (int tm = 0; tm < 4; ++tm) {
#pragma unroll
                    for (int r = 0; r < 4; ++r)
                        lsum += fsig_fast(acc[tm][tn][r] + bv);
                }
            }
        }
        lsum = wave_reduce(lsum);
        if (lane == 0) red[wid] = lsum;
        __syncthreads();
        if (tid == 0)
            psum[blk] = red[0] + red[1] + red[2] + red[3];
    } else if (blk < P2) {
        // ---------------- agg_outcost path (bucketed, LDS accumulate) -----
        int bkt = blk - P1;
        float* agg = (float*)Bsh;   // 64 floats carved from Bsh
        if (tid < BNODES) agg[tid] = 0.0f;
        __syncthreads();
        int cnt = cursor[bkt * CPAD];
        if (cnt > BCAP) cnt = BCAP;
        if (cnt < 0) cnt = 0;
        const uint2* bp = buck + (size_t)bkt * BCAP;
        for (int base = 0; base < cnt; base += 2048) {
            unsigned x[8]; float pv[8]; int ii[8];
#pragma unroll
            for (int j = 0; j < 8; ++j) {
                ii[j] = base + j * 256 + tid;
                x[j] = (ii[j] < cnt) ? bp[ii[j]].x : 0u;
            }
#pragma unroll
            for (int j = 0; j < 8; ++j)
                pv[j] = (ii[j] < cnt) ? pred[x[j] & 0x3FFFF] : 0.f;
#pragma unroll
            for (int j = 0; j < 8; ++j)
                if (ii[j] < cnt) atomicAdd(&agg[(x[j] >> 18) & 63], pv[j]);
        }
        __syncthreads();
        if (tid < 64) {
            float v = 0.f;
            int node = bkt * BNODES + tid;
            if (node < N) {
                float d = agg[tid] - 1.0f;
                v = d * d * sc[node];
            }
            v = wave_reduce(v);
            if (tid == 0) ocpart[bkt] = v;
        }
    } else if (blk < P3) {
        // ---------------- rowcol path (+ce/sq on rows) ----------------
        int rc = blk - P2;
        if (rc < MNUM) {
            float p = 0.f, ce = 0.f, sq = 0.f;
            if (tid < MNUM) {
                p = pred[rc * MNUM + tid];
                ce = -gt[rc * MNUM + tid] * __log2f(p);
                sq = p * p;
            }
            p = wave_reduce(p);
            ce = wave_reduce(ce);
            sq = wave_reduce(sq);
            int wid = tid >> 6;
            if ((tid & 63) == 0) { red[wid] = p; red[4 + wid] = ce; red[8 + wid] = sq; }
            __syncthreads();
            if (tid == 0) {
                rs[rc] = red[0] + red[1] + red[2] + red[3];
                cepart[rc] = red[4] + red[5] + red[6] + red[7];
                sqpart[rc] = red[8] + red[9] + red[10] + red[11];
            }
        } else {
            int j = rc - MNUM;
            float p = 0.f;
            if (tid < MNUM) p = pred[tid * MNUM + j];
            p = wave_reduce(p);
            if ((tid & 63) == 0) red[tid >> 6] = p;
            __syncthreads();
            if (tid == 0) cs[j] = red[0] + red[1] + red[2] + red[3];
        }
    } else {
        // ---------------- gsum dim-reduction ----------------
        int dim = blk - P3;  // 0..127
        float s = 0.f;
        for (int b = tid; b < nbuck; b += 256) s += gpart[(size_t)b * 128 + dim];
        s = wave_reduce(s);
        if ((tid & 63) == 0) red[tid >> 6] = s;
        __syncthreads();
        if (tid == 0) gsum[dim] = red[0] + red[1] + red[2] + red[3];
    }
}

// K8: single-block tail (1024 threads): all six outputs via plain stores.
__global__ __launch_bounds__(1024) void tail_kernel(
        const float* __restrict__ rs, const float* __restrict__ cs,
        const float* __restrict__ cepart, const float* __restrict__ sqpart,
        const float* __restrict__ psum, int npsum,
        const float* __restrict__ ocpart, int nbuck,
        const float* __restrict__ gsum, const float* __restrict__ fc3_w,
        const float* __restrict__ fc3_b, const float* __restrict__ fl3_b,
        float* __restrict__ out, int N, int padrows) {
    __shared__ float red[16];
    int tid = threadIdx.x;
    int wid = tid >> 6, lane = tid & 63;
    // sumone
    float v = 0.f;
    if (tid < MNUM) {
        float a = rs[tid] - 1.0f, b = cs[tid] - 1.0f;
        v = a * a + b * b;
    }
    v = wave_reduce(v);
    if (lane == 0) red[wid] = v;
    __syncthreads();
    if (tid == 0) { float s = 0.f; for (int i = 0; i < 16; ++i) s += red[i]; out[1] = s; }
    __syncthreads();
    // ce
    float ce = (tid < MNUM) ? cepart[tid] : 0.f;
    ce = wave_reduce(ce);
    if (lane == 0) red[wid] = ce;
    __syncthreads();
    if (tid == 0) { float s = 0.f; for (int i = 0; i < 16; ++i) s += red[i]; out[3] = s; }
    __syncthreads();
    // loss2 = sum rs^2 + sum cs^2 - 2 sum p^2
    float l2 = 0.f;
    if (tid < MNUM)
        l2 = rs[tid] * rs[tid] + cs[tid] * cs[tid] - 2.0f * sqpart[tid];
    l2 = wave_reduce(l2);
    if (lane == 0) red[wid] = l2;
    __syncthreads();
    if (tid == 0) { float s = 0.f; for (int i = 0; i < 16; ++i) s += red[i]; out[2] = s; }
    __syncthreads();
    // prob3_sum
    float ps = 0.f;
    for (int i = tid; i < npsum; i += 1024) ps += psum[i];
    float ss = 0.f;
    for (int p = tid; p < PNUM; p += 1024) ss += fsig_fast(fl3_b[p]);
    float comb = ps - (float)padrows * ss;
    comb = wave_reduce(comb);
    if (lane == 0) red[wid] = comb;
    __syncthreads();
    if (tid == 0) { float s = 0.f; for (int i = 0; i < 16; ++i) s += red[i]; out[5] = s; }
    __syncthreads();
    // out_cost
    float oc = 0.f;
    for (int b = tid; b < nbuck; b += 1024) oc += ocpart[b];
    oc = wave_reduce(oc);
    if (lane == 0) red[wid] = oc;
    __syncthreads();
    if (tid == 0) { float s = 0.f; for (int i = 0; i < 16; ++i) s += red[i]; out[4] = s; }
    __syncthreads();
    // pred_obj
    float pv = 0.f;
    if (tid < 128) pv = gsum[tid] * (1.0f / (float)N) * fc3_w[tid];
    pv = wave_reduce(pv);
    if (lane == 0) red[wid] = pv;
    __syncthreads();
    if (tid == 0) { float s = 0.f; for (int i = 0; i < 16; ++i) s += red[i]; out[0] = s + fc3_b[0]; }
}

extern "C" void kernel_launch(void* const* d_in, const int* in_sizes, int n_in,
                              void* d_out, int out_size, void* d_ws, size_t ws_size,
                              hipStream_t stream) {
    const float* ntc   = (const float*)d_in[0];
    const float* norm  = (const float*)d_in[1];
    const float* sc    = (const float*)d_in[2];
    const float* gt    = (const float*)d_in[3];
    const float* fc_w  = (const float*)d_in[4];
    const float* fc_b  = (const float*)d_in[5];
    const float* w_nt  = (const float*)d_in[6];
    const float* w_rel = (const float*)d_in[7];
    const float* fc2_w = (const float*)d_in[8];
    const float* fc2_b = (const float*)d_in[9];
    const float* fc3_w = (const float*)d_in[10];
    const float* fc3_b = (const float*)d_in[11];
    const float* fl3_w = (const float*)d_in[12];
    const float* fl3_b = (const float*)d_in[13];
    const int* node_type = (const int*)d_in[14];
    const int* src   = (const int*)d_in[15];
    const int* dst   = (const int*)d_in[16];
    const int* etype = (const int*)d_in[17];
    int N = in_sizes[2];
    int E = in_sizes[1];
    int nb128 = (N + 127) / 128;             // 391
    int padN  = nb128 * 128;                 // 50048
    int nbuck = padN / BNODES;               // 782
    int npsum = nb128;                       // 391
    int NP = (E + EPB - 1) / EPB;            // 196

    // ---- workspace layout (float offsets) ----
    float* ws   = (float*)d_ws;
    unsigned short* wt = (unsigned short*)ws;            // 0..65536 (131072 shorts)
    float* biasws = ws + 65536;              // ..66560
    float* gsum = ws + 66560;                // ..66688
    float* rs   = ws + 66688;                // ..66944
    float* cs   = ws + 66944;                // ..67200
    int*  cursor = (int*)(ws + 67200);       // ..79744 (12544 ints, padded CPAD=16)
    float* psum = ws + 79744;                // ..80768 (391 used)
    float* cepart = ws + 80768;              // ..81024
    float* sqpart = ws + 81024;              // ..81280
    float* ocpart = ws + 81280;              // ..82304
    unsigned short* CbT = (unsigned short*)(ws + 82304); // 8192 shorts -> ..86400
    float* gpart  = ws + 86400;              // ..186496 (782*128)
    float* pred = ws + 186496;               // ..+N = 236496
    unsigned short* hb = (unsigned short*)(ws + 236496); // padN*128 bf16 -> ..3439568
    uint2* buck = (uint2*)(ws + 3439568);    // nbuck*BCAP*8B
    float* out  = (float*)d_out;

    hipMemsetAsync(cursor, 0, NBUCK * CPAD * sizeof(int), stream);

    partition_setup<<<NP + 130, 1024, 0, stream>>>(src, dst, etype, norm, node_type, ntc,
                                                   cursor, buck, E, NP,
                                                   fl3_w, fl3_b, wt, biasws,
                                                   fc_w, fc_b, w_nt, w_rel, CbT);
    bucket_node<<<nbuck, 256, 0, stream>>>(buck, cursor, CbT, fc2_w, fc2_b,
                                           hb, pred, gpart, N);
    int megablocks = nb128 + nbuck + 2 * MNUM + 128;
    mega_kernel<<<megablocks, 256, 0, stream>>>(hb, wt, biasws, psum, nb128,
                                                buck, cursor, pred, sc, gt, ocpart, N,
                                                rs, cs, cepart, sqpart, gpart, gsum, nbuck);
    tail_kernel<<<1, 1024, 0, stream>>>(rs, cs, cepart, sqpart, psum, npsum, ocpart, nbuck,
                                        gsum, fc3_w, fc3_b, fl3_b, out, N, padN - N);
}